// Round 15
// baseline (616.257 us; speedup 1.0000x reference)
//
#include <hip/hip_runtime.h>
#include <hip/hip_cooperative_groups.h>
#include <math.h>

#define C 128  // IN_C == OUT_C == 128

namespace cg = cooperative_groups;

typedef _Float16 f16x8 __attribute__((ext_vector_type(8)));
typedef _Float16 half2_t __attribute__((ext_vector_type(2)));
typedef __attribute__((ext_vector_type(4))) float f32x4;

static __device__ __forceinline__ unsigned int pkh2(float lo, float hi) {
    unsigned short l = __builtin_bit_cast(unsigned short, (_Float16)lo);
    unsigned short h = __builtin_bit_cast(unsigned short, (_Float16)hi);
    return ((unsigned int)h << 16) | l;
}
static __device__ __forceinline__ float h2f_lo(unsigned int u) {
    return (float)__builtin_bit_cast(_Float16, (unsigned short)(u & 0xFFFFu));
}
static __device__ __forceinline__ float h2f_hi(unsigned int u) {
    return (float)__builtin_bit_cast(_Float16, (unsigned short)(u >> 16));
}
static __device__ __forceinline__ float dot2acc(unsigned int a, unsigned int b, float c) {
#if __has_builtin(__builtin_amdgcn_fdot2)
    return __builtin_amdgcn_fdot2(__builtin_bit_cast(half2_t, a),
                                  __builtin_bit_cast(half2_t, b), c, false);
#else
    c = fmaf(h2f_lo(a), h2f_lo(b), c);
    return fmaf(h2f_hi(a), h2f_hi(b), c);
#endif
}

// ---------------------------------------------------------------------------
// Stage A (fused): [gemm blocks][cast blocks][binhist blocks]
// ---------------------------------------------------------------------------
__global__ __launch_bounds__(256) void k_stageA(const float* __restrict__ x,
                                                const float* __restrict__ Wf0,
                                                unsigned short* __restrict__ xlh,
                                                const float* __restrict__ embf,
                                                unsigned int* __restrict__ embh,
                                                const int* __restrict__ eidx,
                                                int* __restrict__ binCounts,
                                                int N, int E,
                                                int nGemmBlocks, int nCastBlocks,
                                                int totalA8) {
    __shared__ int lh[256];
    const int b = blockIdx.x;

    if (b < nGemmBlocks) {
        // GEMM branch: W cast f32->f16 into LDS once per block, then MFMA.
        __shared__ unsigned int wsh[C * C / 2];   // 32KB
        const int tid = threadIdx.x;
        for (int i = tid; i < C * C / 8; i += 256) {
            const float4 a = ((const float4*)Wf0)[i * 2];
            const float4 bb = ((const float4*)Wf0)[i * 2 + 1];
            uint4 o;
            o.x = pkh2(a.x, a.y); o.y = pkh2(a.z, a.w);
            o.z = pkh2(bb.x, bb.y); o.w = pkh2(bb.z, bb.w);
            ((uint4*)wsh)[i] = o;
        }
        __syncthreads();

        const int lane = threadIdx.x & 63;
        const int wave = threadIdx.x >> 6;
        const int row0 = b * 64 + wave * 16;
        const int r = lane & 15, kg = lane >> 4;

        int arow = row0 + r;
        if (arow >= N) arow = N - 1;
        const float* xrow = x + (size_t)arow * C;
        f16x8 A[4];
#pragma unroll
        for (int kb = 0; kb < 4; ++kb) {
            const float4 p0 = ((const float4*)(xrow + kb * 32 + kg * 8))[0];
            const float4 p1 = ((const float4*)(xrow + kb * 32 + kg * 8))[1];
            f16x8 a;
            a[0] = (_Float16)p0.x; a[1] = (_Float16)p0.y;
            a[2] = (_Float16)p0.z; a[3] = (_Float16)p0.w;
            a[4] = (_Float16)p1.x; a[5] = (_Float16)p1.y;
            a[6] = (_Float16)p1.z; a[7] = (_Float16)p1.w;
            A[kb] = a;
        }

#pragma unroll
        for (int nt = 0; nt < 8; ++nt) {
            const uint4* wrow = (const uint4*)wsh + (size_t)(nt * 16 + r) * 16;
            f32x4 acc = {0.0f, 0.0f, 0.0f, 0.0f};
#pragma unroll
            for (int kb = 0; kb < 4; ++kb) {
                f16x8 B = __builtin_bit_cast(f16x8, wrow[kb * 4 + kg]);
                acc = __builtin_amdgcn_mfma_f32_16x16x32_f16(A[kb], B, acc, 0, 0, 0);
            }
            const int orow = row0 + kg * 4;
            const int ocol = nt * 16 + r;
#pragma unroll
            for (int i = 0; i < 4; ++i)
                if (orow + i < N)
                    xlh[(size_t)(orow + i) * C + ocol] =
                        __builtin_bit_cast(unsigned short, (_Float16)acc[i]);
        }
    } else if (b < nGemmBlocks + nCastBlocks) {
        // cast branch: emb f32 -> packed f16
        int i = (b - nGemmBlocks) * 256 + threadIdx.x;
        if (i >= totalA8) return;
        const float4 a = ((const float4*)embf)[i * 2];
        const float4 bb = ((const float4*)embf)[i * 2 + 1];
        uint4 o;
        o.x = pkh2(a.x, a.y); o.y = pkh2(a.z, a.w);
        o.z = pkh2(bb.x, bb.y); o.w = pkh2(bb.z, bb.w);
        ((uint4*)embh)[i] = o;
    } else {
        // binhist branch
        const int t = threadIdx.x;
        lh[t] = 0;
        __syncthreads();
        const int base = (b - nGemmBlocks - nCastBlocks) * 2048;
#pragma unroll
        for (int j = 0; j < 8; ++j) {
            const int e = base + j * 256 + t;
            if (e < E) atomicAdd(&lh[eidx[E + e] >> 8], 1);
        }
        __syncthreads();
        const int v = lh[t];
        if (v) atomicAdd(&binCounts[t], v);
    }
}

// ---------------------------------------------------------------------------
// Mega (cooperative): bin -> place -> agg -> bnstats -> bnapply, separated by
// grid.sync(). All phases grid-stride over their work. Record u32:
// [31:24]=dst&255, [23:0]=src (needs N < 2^24).
// ---------------------------------------------------------------------------
__global__ __launch_bounds__(256, 4) void k_mega(const int* __restrict__ eidx,
                                                 const int* __restrict__ binCounts,
                                                 int* __restrict__ binAlloc,
                                                 unsigned int* __restrict__ binned,
                                                 int* __restrict__ offs,
                                                 int* __restrict__ src_s,
                                                 const unsigned int* __restrict__ xlh,
                                                 const unsigned int* __restrict__ embh,
                                                 const float* __restrict__ bias,
                                                 float* __restrict__ out,
                                                 float* __restrict__ ssum,
                                                 float* __restrict__ ssq,
                                                 const float* __restrict__ gamma,
                                                 const float* __restrict__ beta,
                                                 int N, int E, int NB,
                                                 int nEdgeBlocks) {
    cg::grid_group grid = cg::this_grid();
    const int t = threadIdx.x;

    // ======================= phase 1: BIN =================================
    {
        __shared__ int lh[256];
        __shared__ int sc[256];
        __shared__ int lb[256];
        for (int bb = blockIdx.x; bb < nEdgeBlocks; bb += gridDim.x) {
            const int v = binCounts[t];
            lh[t] = 0;
            sc[t] = v;
            __syncthreads();
            const int base = bb * 2048;
            int bj[8], rj[8];
            unsigned int recj[8];
#pragma unroll
            for (int j = 0; j < 8; ++j) {
                const int e = base + j * 256 + t;
                bj[j] = -1;
                if (e < E) {
                    const int s = eidx[e];
                    const int d = eidx[E + e];
                    bj[j] = d >> 8;
                    recj[j] = ((unsigned)(d & 255) << 24) | (unsigned)s;
                    rj[j] = atomicAdd(&lh[bj[j]], 1);
                }
            }
            __syncthreads();
            for (int o = 1; o < 256; o <<= 1) {
                int u = (t >= o) ? sc[t - o] : 0;
                __syncthreads();
                sc[t] += u;
                __syncthreads();
            }
            const int excl = sc[t] - v;
            const int c = lh[t];
            if (c) lb[t] = excl + atomicAdd(&binAlloc[t], c);
            __syncthreads();
#pragma unroll
            for (int j = 0; j < 8; ++j) {
                if (bj[j] >= 0) binned[lb[bj[j]] + rj[j]] = recj[j];
            }
            __syncthreads();
        }
    }
    grid.sync();

    // ======================= phase 2: PLACE ================================
    {
        __shared__ int sc[256];
        __shared__ int cnt[256];
        __shared__ int ts[256];
        __shared__ int cur[256];
        __shared__ int r0s, r1s;
        for (int b = blockIdx.x; b < NB; b += gridDim.x) {
            const int node0 = b * 256;
            const int v0 = binCounts[t];
            sc[t] = v0;
            cnt[t] = 0;
            __syncthreads();
            for (int o = 1; o < 256; o <<= 1) {
                int u = (t >= o) ? sc[t - o] : 0;
                __syncthreads();
                sc[t] += u;
                __syncthreads();
            }
            if (t == b) { r0s = sc[t] - v0; r1s = sc[t]; }
            __syncthreads();
            const int r0 = r0s, r1 = r1s;
            for (int i = r0 + t; i < r1; i += 256)
                atomicAdd(&cnt[binned[i] >> 24], 1);
            __syncthreads();
            const int v = cnt[t];
            ts[t] = v;
            __syncthreads();
            for (int o = 1; o < 256; o <<= 1) {
                int u = (t >= o) ? ts[t - o] : 0;
                __syncthreads();
                ts[t] += u;
                __syncthreads();
            }
            const int excl = r0 + ts[t] - v;
            if (node0 + t < N) offs[node0 + t] = excl;
            cur[t] = excl;
            __syncthreads();
            for (int i = r0 + t; i < r1; i += 256) {
                const unsigned int rec = binned[i];
                const int pos = atomicAdd(&cur[rec >> 24], 1);
                src_s[pos] = (int)(rec & 0xFFFFFFu);
            }
            if (b == NB - 1 && t == 0) offs[N] = E;
            __syncthreads();
        }
    }
    grid.sync();

    // ======================= phase 3: AGG ==================================
    {
        const int lane = t & 63;
        const int wave = t >> 6;
        const int g = lane >> 3;
        const int sl = lane & 7;
        const int totalWaves = (int)gridDim.x * 4;
        for (int node = (int)blockIdx.x * 4 + wave; node < N; node += totalWaves) {
            const int s0 = offs[node], s1 = offs[node + 1];
            const uint4* erow = (const uint4*)(embh + (size_t)node * (C / 2));
            const uint4 e0 = erow[sl * 2], e1 = erow[sl * 2 + 1];

            float p = 0.0f;
            p = dot2acc(e0.x, e0.x, p); p = dot2acc(e0.y, e0.y, p);
            p = dot2acc(e0.z, e0.z, p); p = dot2acc(e0.w, e0.w, p);
            p = dot2acc(e1.x, e1.x, p); p = dot2acc(e1.y, e1.y, p);
            p = dot2acc(e1.z, e1.z, p); p = dot2acc(e1.w, e1.w, p);
            p += __shfl_xor(p, 4); p += __shfl_xor(p, 2); p += __shfl_xor(p, 1);

            float m = p;
            float wself = 1.0f;
            float dex = 0.0f;
            float dpart = 0.0f;
            const unsigned int xw = xlh[(size_t)node * (C / 2) + lane];
            float2 acc = {h2f_lo(xw), h2f_hi(xw)};

            for (int base = s0; base < s1; base += 64) {
                int mys = -1;
                if (base + lane < s1) mys = src_s[base + lane];
                const int iters = min(8, (s1 - base + 7) >> 3);
                for (int k = 0; k < iters; ++k) {
                    const int sg = __shfl(mys, k * 8 + g);
                    const int sa = (sg >= 0) ? sg : node;

                    const uint4* vrow = (const uint4*)(embh + (size_t)sa * (C / 2));
                    const uint4 v0 = vrow[sl * 2], v1 = vrow[sl * 2 + 1];
                    float a = 0.0f;
                    a = dot2acc(e0.x, v0.x, a); a = dot2acc(e0.y, v0.y, a);
                    a = dot2acc(e0.z, v0.z, a); a = dot2acc(e0.w, v0.w, a);
                    a = dot2acc(e1.x, v1.x, a); a = dot2acc(e1.y, v1.y, a);
                    a = dot2acc(e1.z, v1.z, a); a = dot2acc(e1.w, v1.w, a);
                    a += __shfl_xor(a, 4); a += __shfl_xor(a, 2); a += __shfl_xor(a, 1);

                    const bool valid = sg >= 0;
                    const bool hot = valid && (a > m - 28.0f);
                    if (__any(hot)) {
                        const unsigned long long bal = __ballot(hot);
#pragma unroll 1
                        for (int j = 0; j < 8; ++j) {
                            if (!((bal >> (j * 8)) & 1ULL)) continue;
                            const float aj = __shfl(a, j * 8);
                            const int sj = __shfl(mys, k * 8 + j);
                            if (aj > m) {
                                const float cs = __expf(m - aj);
                                dpart *= cs; dex *= cs; wself *= cs;
                                acc.x *= cs; acc.y *= cs;
                                m = aj;
                            }
                            const float w = __expf(aj - m);
                            dex += w;
                            if (w > 1e-12f) {
                                const unsigned int u = xlh[(size_t)sj * (C / 2) + lane];
                                acc.x = fmaf(w, h2f_lo(u), acc.x);
                                acc.y = fmaf(w, h2f_hi(u), acc.y);
                            }
                        }
                    }
                    dpart += (valid && !hot) ? __expf(a - m) : 0.0f;
                }
            }

            float dg = dpart;
            dg += __shfl_xor(dg, 8); dg += __shfl_xor(dg, 16); dg += __shfl_xor(dg, 32);
            const float dtot = wself + dex + dg;
            const float inv = 1.0f / (dtot + 1e-16f);
            const int c = lane * 2;
            float2 o2;
            o2.x = fmaf(acc.x, inv, bias[c]);
            o2.y = fmaf(acc.y, inv, bias[c + 1]);
            ((float2*)(out + (size_t)node * C))[lane] = o2;
        }
    }
    grid.sync();

    // ======================= phase 4: BN STATS =============================
    {
        __shared__ float4 lsum[256];
        __shared__ float4 lsq[256];
        const int total4 = N * (C / 4);
        const int stride = (int)gridDim.x * 256;     // multiple of 32
        float4 s4 = {0, 0, 0, 0}, q4 = {0, 0, 0, 0};
        for (int i = (int)blockIdx.x * 256 + t; i < total4; i += stride) {
            float4 v = ((const float4*)out)[i];
            s4.x += v.x; s4.y += v.y; s4.z += v.z; s4.w += v.w;
            q4.x = fmaf(v.x, v.x, q4.x); q4.y = fmaf(v.y, v.y, q4.y);
            q4.z = fmaf(v.z, v.z, q4.z); q4.w = fmaf(v.w, v.w, q4.w);
        }
        lsum[t] = s4; lsq[t] = q4;
        __syncthreads();
        if (t < 32) {
            float4 S = lsum[t], Q = lsq[t];
#pragma unroll
            for (int j = 1; j < 8; ++j) {
                float4 a = lsum[t + 32 * j], b = lsq[t + 32 * j];
                S.x += a.x; S.y += a.y; S.z += a.z; S.w += a.w;
                Q.x += b.x; Q.y += b.y; Q.z += b.z; Q.w += b.w;
            }
            const int c = t * 4;
            atomicAdd(&ssum[c], S.x);     atomicAdd(&ssum[c + 1], S.y);
            atomicAdd(&ssum[c + 2], S.z); atomicAdd(&ssum[c + 3], S.w);
            atomicAdd(&ssq[c], Q.x);      atomicAdd(&ssq[c + 1], Q.y);
            atomicAdd(&ssq[c + 2], Q.z);  atomicAdd(&ssq[c + 3], Q.w);
        }
    }
    grid.sync();

    // ======================= phase 5: BN APPLY + ReLU ======================
    {
        const int total4 = N * (C / 4);
        const int stride = (int)gridDim.x * 256;
        const float invN = 1.0f / (float)N;
        for (int idx = (int)blockIdx.x * 256 + t; idx < total4; idx += stride) {
            const int c = (idx * 4) & 127;
            float4 v = ((float4*)out)[idx];
            float r[4] = {v.x, v.y, v.z, v.w};
#pragma unroll
            for (int j = 0; j < 4; ++j) {
                float mu = ssum[c + j] * invN;
                float var = fmaf(-mu, mu, ssq[c + j] * invN);
                var = fmaxf(var, 0.0f);
                float sc2 = gamma[c + j] / sqrtf(var + 1e-5f);
                float val = fmaf(r[j] - mu, sc2, beta[c + j]);
                r[j] = fmaxf(val, 0.0f);
            }
            float4 o = {r[0], r[1], r[2], r[3]};
            ((float4*)out)[idx] = o;
        }
    }
}

// ---------------------------------------------------------------------------
extern "C" void kernel_launch(void* const* d_in, const int* in_sizes, int n_in,
                              void* d_out, int out_size, void* d_ws, size_t ws_size,
                              hipStream_t stream) {
    const float* x     = (const float*)d_in[0];
    const int*   eidx  = (const int*)d_in[1];   // [2][E]
    const float* emb   = (const float*)d_in[2];
    const float* W     = (const float*)d_in[3];
    const float* bias  = (const float*)d_in[4];
    const float* gamma = (const float*)d_in[5];
    const float* beta  = (const float*)d_in[6];
    const int N = in_sizes[0] / C;
    const int E = in_sizes[1] / 2;
    float* out = (float*)d_out;

    char* ws = (char*)d_ws;
    size_t off = 0;
    auto alloc = [&](size_t bytes) -> void* {
        void* p = ws + off;
        off = (off + bytes + 255) & ~(size_t)255;
        return p;
    };
    unsigned short* xlh  = (unsigned short*)alloc((size_t)N * C * 2);
    unsigned int*   embh = (unsigned int*)  alloc((size_t)N * C * 2);
    int*   src_s    = (int*)  alloc((size_t)E * 4);
    unsigned int* binned = (unsigned int*)alloc((size_t)E * 4);
    int*   offs     = (int*)  alloc((size_t)(N + 1) * 4);
    // contiguous zero-init region: binCounts + binAlloc + ssum + ssq
    char*  zbase    = (char*)alloc(0);
    int*   binCounts= (int*)  alloc(256 * 4);
    int*   binAlloc = (int*)  alloc(256 * 4);
    float* ssum     = (float*)alloc(C * 4);
    float* ssq      = (float*)alloc(C * 4);
    size_t zbytes   = (char*)ws + off - zbase;

    int NB = (N + 255) / 256;                    // 196 bins (<= 256)
    int nEdgeBlocks = (E + 2047) / 2048;         // 391
    const int embTot8 = N * (C / 8);
    const int nGemmBlocks = (N + 63) / 64;       // 782
    const int nCastBlocks = (embTot8 + 255) / 256;

    hipMemsetAsync(zbase, 0, zbytes, stream);

    k_stageA <<<nGemmBlocks + nCastBlocks + nEdgeBlocks, 256, 0, stream>>>(
                 x, W, xlh, emb, embh, eidx, binCounts,
                 N, E, nGemmBlocks, nCastBlocks, embTot8);

    {
        const int* eidx_a = eidx;
        const int* binCounts_a = binCounts;
        int* binAlloc_a = binAlloc;
        unsigned int* binned_a = binned;
        int* offs_a = offs;
        int* src_a = src_s;
        const unsigned int* xlh_a = (const unsigned int*)xlh;
        const unsigned int* embh_a = embh;
        const float* bias_a = bias;
        float* out_a = out;
        float* ssum_a = ssum;
        float* ssq_a = ssq;
        const float* gamma_a = gamma;
        const float* beta_a = beta;
        int N_a = N, E_a = E, NB_a = NB, nEB_a = nEdgeBlocks;
        void* args[] = {
            (void*)&eidx_a, (void*)&binCounts_a, (void*)&binAlloc_a,
            (void*)&binned_a, (void*)&offs_a, (void*)&src_a,
            (void*)&xlh_a, (void*)&embh_a, (void*)&bias_a, (void*)&out_a,
            (void*)&ssum_a, (void*)&ssq_a, (void*)&gamma_a, (void*)&beta_a,
            (void*)&N_a, (void*)&E_a, (void*)&NB_a, (void*)&nEB_a
        };
        hipLaunchCooperativeKernel((const void*)k_mega, dim3(1024), dim3(256),
                                   args, 0, stream);
    }
}

// Round 16
// 121.168 us; speedup vs baseline: 5.0860x; 5.0860x over previous
//
#include <hip/hip_runtime.h>
#include <math.h>

#define C 128  // IN_C == OUT_C == 128

typedef _Float16 f16x8 __attribute__((ext_vector_type(8)));
typedef _Float16 half2_t __attribute__((ext_vector_type(2)));
typedef __attribute__((ext_vector_type(4))) float f32x4;

static __device__ __forceinline__ unsigned int pkh2(float lo, float hi) {
    unsigned short l = __builtin_bit_cast(unsigned short, (_Float16)lo);
    unsigned short h = __builtin_bit_cast(unsigned short, (_Float16)hi);
    return ((unsigned int)h << 16) | l;
}
static __device__ __forceinline__ float h2f_lo(unsigned int u) {
    return (float)__builtin_bit_cast(_Float16, (unsigned short)(u & 0xFFFFu));
}
static __device__ __forceinline__ float h2f_hi(unsigned int u) {
    return (float)__builtin_bit_cast(_Float16, (unsigned short)(u >> 16));
}
static __device__ __forceinline__ float dot2acc(unsigned int a, unsigned int b, float c) {
#if __has_builtin(__builtin_amdgcn_fdot2)
    return __builtin_amdgcn_fdot2(__builtin_bit_cast(half2_t, a),
                                  __builtin_bit_cast(half2_t, b), c, false);
#else
    c = fmaf(h2f_lo(a), h2f_lo(b), c);
    return fmaf(h2f_hi(a), h2f_hi(b), c);
#endif
}

// ---------------------------------------------------------------------------
// Stage A (fused): [gemm blocks][cast blocks][binhist blocks]
// ---------------------------------------------------------------------------
__global__ __launch_bounds__(256) void k_stageA(const float* __restrict__ x,
                                                const float* __restrict__ Wf0,
                                                unsigned short* __restrict__ xlh,
                                                const float* __restrict__ embf,
                                                unsigned int* __restrict__ embh,
                                                const int* __restrict__ eidx,
                                                int* __restrict__ binCounts,
                                                int N, int E,
                                                int nGemmBlocks, int nCastBlocks,
                                                int totalA8) {
    __shared__ int lh[256];
    const int b = blockIdx.x;

    if (b < nGemmBlocks) {
        // GEMM branch: W cast f32->f16 into LDS once per block, then MFMA.
        __shared__ unsigned int wsh[C * C / 2];   // 32KB
        const int tid = threadIdx.x;
        for (int i = tid; i < C * C / 8; i += 256) {
            const float4 a = ((const float4*)Wf0)[i * 2];
            const float4 bb = ((const float4*)Wf0)[i * 2 + 1];
            uint4 o;
            o.x = pkh2(a.x, a.y); o.y = pkh2(a.z, a.w);
            o.z = pkh2(bb.x, bb.y); o.w = pkh2(bb.z, bb.w);
            ((uint4*)wsh)[i] = o;
        }
        __syncthreads();

        const int lane = threadIdx.x & 63;
        const int wave = threadIdx.x >> 6;
        const int row0 = b * 64 + wave * 16;
        const int r = lane & 15, kg = lane >> 4;

        int arow = row0 + r;
        if (arow >= N) arow = N - 1;
        const float* xrow = x + (size_t)arow * C;
        f16x8 A[4];
#pragma unroll
        for (int kb = 0; kb < 4; ++kb) {
            const float4 p0 = ((const float4*)(xrow + kb * 32 + kg * 8))[0];
            const float4 p1 = ((const float4*)(xrow + kb * 32 + kg * 8))[1];
            f16x8 a;
            a[0] = (_Float16)p0.x; a[1] = (_Float16)p0.y;
            a[2] = (_Float16)p0.z; a[3] = (_Float16)p0.w;
            a[4] = (_Float16)p1.x; a[5] = (_Float16)p1.y;
            a[6] = (_Float16)p1.z; a[7] = (_Float16)p1.w;
            A[kb] = a;
        }

#pragma unroll
        for (int nt = 0; nt < 8; ++nt) {
            const uint4* wrow = (const uint4*)wsh + (size_t)(nt * 16 + r) * 16;
            f32x4 acc = {0.0f, 0.0f, 0.0f, 0.0f};
#pragma unroll
            for (int kb = 0; kb < 4; ++kb) {
                f16x8 B = __builtin_bit_cast(f16x8, wrow[kb * 4 + kg]);
                acc = __builtin_amdgcn_mfma_f32_16x16x32_f16(A[kb], B, acc, 0, 0, 0);
            }
            const int orow = row0 + kg * 4;
            const int ocol = nt * 16 + r;
#pragma unroll
            for (int i = 0; i < 4; ++i)
                if (orow + i < N)
                    xlh[(size_t)(orow + i) * C + ocol] =
                        __builtin_bit_cast(unsigned short, (_Float16)acc[i]);
        }
    } else if (b < nGemmBlocks + nCastBlocks) {
        // cast branch: emb f32 -> packed f16
        int i = (b - nGemmBlocks) * 256 + threadIdx.x;
        if (i >= totalA8) return;
        const float4 a = ((const float4*)embf)[i * 2];
        const float4 bb = ((const float4*)embf)[i * 2 + 1];
        uint4 o;
        o.x = pkh2(a.x, a.y); o.y = pkh2(a.z, a.w);
        o.z = pkh2(bb.x, bb.y); o.w = pkh2(bb.z, bb.w);
        ((uint4*)embh)[i] = o;
    } else {
        // binhist branch
        const int t = threadIdx.x;
        lh[t] = 0;
        __syncthreads();
        const int base = (b - nGemmBlocks - nCastBlocks) * 2048;
#pragma unroll
        for (int j = 0; j < 8; ++j) {
            const int e = base + j * 256 + t;
            if (e < E) atomicAdd(&lh[eidx[E + e] >> 8], 1);
        }
        __syncthreads();
        const int v = lh[t];
        if (v) atomicAdd(&binCounts[t], v);
    }
}

// ---------------------------------------------------------------------------
// k_bin: local LDS scan of binCounts; space claimed per (block,bin) on
// binAlloc; grouped contiguous record writes. Record u32: [31:24]=dst&255,
// [23:0]=src (needs N < 2^24).
// ---------------------------------------------------------------------------
__global__ __launch_bounds__(256) void k_bin(const int* __restrict__ eidx,
                                             const int* __restrict__ binCounts,
                                             int* __restrict__ binAlloc,
                                             unsigned int* __restrict__ binned, int E) {
    __shared__ int lh[256];
    __shared__ int sc[256];
    __shared__ int lb[256];
    const int t = threadIdx.x;
    const int v = binCounts[t];          // bins >= NB hold 0
    lh[t] = 0;
    sc[t] = v;
    __syncthreads();
    const int base = blockIdx.x * 2048;
    int bj[8], rj[8];
    unsigned int recj[8];
#pragma unroll
    for (int j = 0; j < 8; ++j) {
        const int e = base + j * 256 + t;
        bj[j] = -1;
        if (e < E) {
            const int s = eidx[e];
            const int d = eidx[E + e];
            bj[j] = d >> 8;
            recj[j] = ((unsigned)(d & 255) << 24) | (unsigned)s;
            rj[j] = atomicAdd(&lh[bj[j]], 1);
        }
    }
    __syncthreads();
    for (int o = 1; o < 256; o <<= 1) {
        int u = (t >= o) ? sc[t - o] : 0;
        __syncthreads();
        sc[t] += u;
        __syncthreads();
    }
    const int excl = sc[t] - v;          // global bin offset
    const int c = lh[t];
    if (c) lb[t] = excl + atomicAdd(&binAlloc[t], c);
    __syncthreads();
#pragma unroll
    for (int j = 0; j < 8; ++j) {
        if (bj[j] >= 0) binned[lb[bj[j]] + rj[j]] = recj[j];
    }
}

// ---------------------------------------------------------------------------
// k_place: one block per bin; local LDS scan of binCounts gives the record
// range; per-node counts + offsets via LDS scan; place src ids with LDS
// cursors (zero global atomics; writes land in the bin's L2-hot window).
// ---------------------------------------------------------------------------
__global__ __launch_bounds__(256) void k_place(const unsigned int* __restrict__ binned,
                                               const int* __restrict__ binCounts,
                                               int* __restrict__ offs,
                                               int* __restrict__ src_s,
                                               int N, int E, int NB) {
    __shared__ int sc[256];
    __shared__ int cnt[256];
    __shared__ int ts[256];
    __shared__ int cur[256];
    __shared__ int r0s, r1s;
    const int b = blockIdx.x;
    const int t = threadIdx.x;
    const int node0 = b * 256;
    const int v0 = binCounts[t];
    sc[t] = v0;
    cnt[t] = 0;
    __syncthreads();
    for (int o = 1; o < 256; o <<= 1) {
        int u = (t >= o) ? sc[t - o] : 0;
        __syncthreads();
        sc[t] += u;
        __syncthreads();
    }
    if (t == b) { r0s = sc[t] - v0; r1s = sc[t]; }
    __syncthreads();
    const int r0 = r0s, r1 = r1s;
    for (int i = r0 + t; i < r1; i += 256)
        atomicAdd(&cnt[binned[i] >> 24], 1);
    __syncthreads();
    const int v = cnt[t];
    ts[t] = v;
    __syncthreads();
    for (int o = 1; o < 256; o <<= 1) {
        int u = (t >= o) ? ts[t - o] : 0;
        __syncthreads();
        ts[t] += u;
        __syncthreads();
    }
    const int excl = r0 + ts[t] - v;
    if (node0 + t < N) offs[node0 + t] = excl;
    cur[t] = excl;
    __syncthreads();
    for (int i = r0 + t; i < r1; i += 256) {
        const unsigned int rec = binned[i];
        const int pos = atomicAdd(&cur[rec >> 24], 1);
        src_s[pos] = (int)(rec & 0xFFFFFFu);
    }
    if (b == NB - 1 && t == 0) offs[N] = E;
}

// ---------------------------------------------------------------------------
// K4: fused attention + online softmax + aggregation (+ BN partial stats).
// One wave per node; 64-edge src batches; 8-lane group dots (f16 v_dot2).
// Cold path: per-group denominator partial. Hot path (ballot, a > m-28):
// exact rescale + denominator + xl gather when w > 1e-12. Epilogue: block
// LDS-reduces its 4 nodes' outputs into 64-way-spread global partial
// buffers (psum/psq) — replaces the full-array bnstats pass.
// ---------------------------------------------------------------------------
__global__ __launch_bounds__(256) void k_agg(const unsigned int* __restrict__ xlh,
                                             const unsigned int* __restrict__ embh,
                                             const int* __restrict__ src_s,
                                             const int* __restrict__ offs,
                                             const float* __restrict__ bias,
                                             float* __restrict__ out,
                                             float* __restrict__ psum,
                                             float* __restrict__ psq, int N) {
    const int node = (int)((blockIdx.x * (size_t)blockDim.x + threadIdx.x) >> 6);
    const int lane = threadIdx.x & 63;
    const int wave = threadIdx.x >> 6;
    const bool active = node < N;
    float2 o2 = {0.0f, 0.0f};

    if (active) {
        const int g = lane >> 3;        // edge slot 0..7
        const int sl = lane & 7;        // sub-lane within 8-group
        const int s0 = offs[node], s1 = offs[node + 1];

        const uint4* erow = (const uint4*)(embh + (size_t)node * (C / 2));
        const uint4 e0 = erow[sl * 2], e1 = erow[sl * 2 + 1];

        // self-loop logit = ||emb[node]||^2
        float p = 0.0f;
        p = dot2acc(e0.x, e0.x, p); p = dot2acc(e0.y, e0.y, p);
        p = dot2acc(e0.z, e0.z, p); p = dot2acc(e0.w, e0.w, p);
        p = dot2acc(e1.x, e1.x, p); p = dot2acc(e1.y, e1.y, p);
        p = dot2acc(e1.z, e1.z, p); p = dot2acc(e1.w, e1.w, p);
        p += __shfl_xor(p, 4); p += __shfl_xor(p, 2); p += __shfl_xor(p, 1);

        float m = p;          // running max (self included)
        float wself = 1.0f;   // exp(self - m)
        float dex = 0.0f;     // hot-path denominator (wave-uniform)
        float dpart = 0.0f;   // per-group denominator partial
        const unsigned int xw = xlh[(size_t)node * (C / 2) + lane];
        float2 acc = {h2f_lo(xw), h2f_hi(xw)};   // wself * xl[node]

        for (int base = s0; base < s1; base += 64) {
            int mys = -1;
            if (base + lane < s1) mys = src_s[base + lane];
            const int iters = min(8, (s1 - base + 7) >> 3);
            for (int k = 0; k < iters; ++k) {
                const int sg = __shfl(mys, k * 8 + g);
                const int sa = (sg >= 0) ? sg : node;

                // group dot: alpha = emb[node] . emb[src]
                const uint4* vrow = (const uint4*)(embh + (size_t)sa * (C / 2));
                const uint4 v0 = vrow[sl * 2], v1 = vrow[sl * 2 + 1];
                float a = 0.0f;
                a = dot2acc(e0.x, v0.x, a); a = dot2acc(e0.y, v0.y, a);
                a = dot2acc(e0.z, v0.z, a); a = dot2acc(e0.w, v0.w, a);
                a = dot2acc(e1.x, v1.x, a); a = dot2acc(e1.y, v1.y, a);
                a = dot2acc(e1.z, v1.z, a); a = dot2acc(e1.w, v1.w, a);
                a += __shfl_xor(a, 4); a += __shfl_xor(a, 2); a += __shfl_xor(a, 1);

                const bool valid = sg >= 0;
                const bool hot = valid && (a > m - 28.0f);
                if (__any(hot)) {
                    const unsigned long long bal = __ballot(hot);
#pragma unroll 1
                    for (int j = 0; j < 8; ++j) {
                        if (!((bal >> (j * 8)) & 1ULL)) continue;
                        const float aj = __shfl(a, j * 8);
                        const int sj = __shfl(mys, k * 8 + j);
                        if (aj > m) {            // wave-uniform rescale
                            const float cs = __expf(m - aj);
                            dpart *= cs; dex *= cs; wself *= cs;
                            acc.x *= cs; acc.y *= cs;
                            m = aj;
                        }
                        const float w = __expf(aj - m);
                        dex += w;
                        if (w > 1e-12f) {
                            const unsigned int u = xlh[(size_t)sj * (C / 2) + lane];
                            acc.x = fmaf(w, h2f_lo(u), acc.x);
                            acc.y = fmaf(w, h2f_hi(u), acc.y);
                        }
                    }
                }
                dpart += (valid && !hot) ? __expf(a - m) : 0.0f;
            }
        }

        float dg = dpart;
        dg += __shfl_xor(dg, 8); dg += __shfl_xor(dg, 16); dg += __shfl_xor(dg, 32);
        const float dtot = wself + dex + dg;
        const float inv = 1.0f / (dtot + 1e-16f);
        const int c = lane * 2;
        o2.x = fmaf(acc.x, inv, bias[c]);
        o2.y = fmaf(acc.y, inv, bias[c + 1]);
        ((float2*)(out + (size_t)node * C))[lane] = o2;
    }

    // ---- BN partial stats: block-level reduce over its 4 nodes, then
    // atomics into a 64-way-spread partial buffer (195 collisions/address).
    __shared__ float2 lsum[256];
    __shared__ float2 lsq[256];
    lsum[threadIdx.x] = o2;
    float2 q2v;
    q2v.x = o2.x * o2.x;
    q2v.y = o2.y * o2.y;
    lsq[threadIdx.x] = q2v;
    __syncthreads();
    if (wave == 0) {
        float2 S = lsum[lane], Q = lsq[lane];
#pragma unroll
        for (int j = 1; j < 4; ++j) {
            const float2 a = lsum[j * 64 + lane];
            const float2 b = lsq[j * 64 + lane];
            S.x += a.x; S.y += a.y;
            Q.x += b.x; Q.y += b.y;
        }
        const int slot = ((int)blockIdx.x & 63) * C + lane * 2;
        atomicAdd(&psum[slot],     S.x);
        atomicAdd(&psum[slot + 1], S.y);
        atomicAdd(&psq[slot],      Q.x);
        atomicAdd(&psq[slot + 1],  Q.y);
    }
}

// ---------------------------------------------------------------------------
// K5: reduce the 64x128 partial buffers into final ssum/ssq (one block).
// ---------------------------------------------------------------------------
__global__ __launch_bounds__(128) void k_bnreduce(const float* __restrict__ psum,
                                                  const float* __restrict__ psq,
                                                  float* __restrict__ ssum,
                                                  float* __restrict__ ssq) {
    const int t = threadIdx.x;   // channel 0..127
    float S = 0.0f, Q = 0.0f;
#pragma unroll 4
    for (int b = 0; b < 64; ++b) {
        S += psum[b * C + t];
        Q += psq[b * C + t];
    }
    ssum[t] = S;
    ssq[t] = Q;
}

// ---------------------------------------------------------------------------
// K6: in-place BN apply (training-mode batch stats, biased var) + ReLU
// ---------------------------------------------------------------------------
__global__ __launch_bounds__(256) void k_bnapply(float* __restrict__ out,
                                                 const float* __restrict__ ssum,
                                                 const float* __restrict__ ssq,
                                                 const float* __restrict__ gamma,
                                                 const float* __restrict__ beta,
                                                 int N) {
    const int idx = blockIdx.x * blockDim.x + threadIdx.x;   // float4 index
    const int total = N * (C / 4);
    if (idx >= total) return;
    const int c = (idx * 4) & 127;
    float4 v = ((const float4*)out)[idx];
    const float invN = 1.0f / (float)N;
    float r[4] = {v.x, v.y, v.z, v.w};
#pragma unroll
    for (int j = 0; j < 4; ++j) {
        float mu = ssum[c + j] * invN;
        float var = fmaf(-mu, mu, ssq[c + j] * invN);
        var = fmaxf(var, 0.0f);
        float sc = gamma[c + j] / sqrtf(var + 1e-5f);
        float val = fmaf(r[j] - mu, sc, beta[c + j]);
        r[j] = fmaxf(val, 0.0f);
    }
    float4 o = {r[0], r[1], r[2], r[3]};
    ((float4*)out)[idx] = o;
}

// ---------------------------------------------------------------------------
extern "C" void kernel_launch(void* const* d_in, const int* in_sizes, int n_in,
                              void* d_out, int out_size, void* d_ws, size_t ws_size,
                              hipStream_t stream) {
    const float* x     = (const float*)d_in[0];
    const int*   eidx  = (const int*)d_in[1];   // [2][E]
    const float* emb   = (const float*)d_in[2];
    const float* W     = (const float*)d_in[3];
    const float* bias  = (const float*)d_in[4];
    const float* gamma = (const float*)d_in[5];
    const float* beta  = (const float*)d_in[6];
    const int N = in_sizes[0] / C;
    const int E = in_sizes[1] / 2;
    float* out = (float*)d_out;

    char* ws = (char*)d_ws;
    size_t off = 0;
    auto alloc = [&](size_t bytes) -> void* {
        void* p = ws + off;
        off = (off + bytes + 255) & ~(size_t)255;
        return p;
    };
    unsigned short* xlh  = (unsigned short*)alloc((size_t)N * C * 2);
    unsigned int*   embh = (unsigned int*)  alloc((size_t)N * C * 2);
    int*   src_s    = (int*)  alloc((size_t)E * 4);
    unsigned int* binned = (unsigned int*)alloc((size_t)E * 4);
    int*   offs     = (int*)  alloc((size_t)(N + 1) * 4);
    float* ssum     = (float*)alloc(C * 4);
    float* ssq      = (float*)alloc(C * 4);
    // contiguous zero-init region: binCounts + binAlloc + psum + psq
    char*  zbase    = (char*)alloc(0);
    int*   binCounts= (int*)  alloc(256 * 4);
    int*   binAlloc = (int*)  alloc(256 * 4);
    float* psum     = (float*)alloc(64 * C * 4);
    float* psq      = (float*)alloc(64 * C * 4);
    size_t zbytes   = (char*)ws + off - zbase;

    const int NB = (N + 255) / 256;              // 196 bins (<= 256)
    const int nEdgeBlocks = (E + 2047) / 2048;   // 391
    const int embTot8 = N * (C / 8);
    const int nGemmBlocks = (N + 63) / 64;       // 782
    const int nCastBlocks = (embTot8 + 255) / 256;

    hipMemsetAsync(zbase, 0, zbytes, stream);

    k_stageA <<<nGemmBlocks + nCastBlocks + nEdgeBlocks, 256, 0, stream>>>(
                 x, W, xlh, emb, embh, eidx, binCounts,
                 N, E, nGemmBlocks, nCastBlocks, embTot8);
    k_bin    <<<nEdgeBlocks,     256, 0, stream>>>(eidx, binCounts, binAlloc, binned, E);
    k_place  <<<NB,              256, 0, stream>>>(binned, binCounts, offs, src_s, N, E, NB);
    k_agg    <<<(int)(((size_t)N * 64 + 255) / 256), 256, 0, stream>>>(
                 (const unsigned int*)xlh, embh, src_s, offs, bias, out,
                 psum, psq, N);
    k_bnreduce<<<1,              128, 0, stream>>>(psum, psq, ssum, ssq);
    k_bnapply<<<(N * (C / 4) + 255) / 256, 256, 0, stream>>>(out, ssum, ssq, gamma, beta, N);
}

// Round 17
// 117.675 us; speedup vs baseline: 5.2370x; 1.0297x over previous
//
#include <hip/hip_runtime.h>
#include <math.h>

#define C 128  // IN_C == OUT_C == 128

typedef _Float16 f16x8 __attribute__((ext_vector_type(8)));
typedef _Float16 half2_t __attribute__((ext_vector_type(2)));
typedef __attribute__((ext_vector_type(4))) float f32x4;

static __device__ __forceinline__ unsigned int pkh2(float lo, float hi) {
    unsigned short l = __builtin_bit_cast(unsigned short, (_Float16)lo);
    unsigned short h = __builtin_bit_cast(unsigned short, (_Float16)hi);
    return ((unsigned int)h << 16) | l;
}
static __device__ __forceinline__ float h2f_lo(unsigned int u) {
    return (float)__builtin_bit_cast(_Float16, (unsigned short)(u & 0xFFFFu));
}
static __device__ __forceinline__ float h2f_hi(unsigned int u) {
    return (float)__builtin_bit_cast(_Float16, (unsigned short)(u >> 16));
}
static __device__ __forceinline__ float dot2acc(unsigned int a, unsigned int b, float c) {
#if __has_builtin(__builtin_amdgcn_fdot2)
    return __builtin_amdgcn_fdot2(__builtin_bit_cast(half2_t, a),
                                  __builtin_bit_cast(half2_t, b), c, false);
#else
    c = fmaf(h2f_lo(a), h2f_lo(b), c);
    return fmaf(h2f_hi(a), h2f_hi(b), c);
#endif
}

// ---------------------------------------------------------------------------
// Stage A (fused): [gemm blocks][cast blocks][binhist blocks]
// ---------------------------------------------------------------------------
__global__ __launch_bounds__(256) void k_stageA(const float* __restrict__ x,
                                                const float* __restrict__ Wf0,
                                                unsigned short* __restrict__ xlh,
                                                const float* __restrict__ embf,
                                                unsigned int* __restrict__ embh,
                                                const int* __restrict__ eidx,
                                                int* __restrict__ binCounts,
                                                int N, int E,
                                                int nGemmBlocks, int nCastBlocks,
                                                int totalA8) {
    __shared__ int lh[256];
    const int b = blockIdx.x;

    if (b < nGemmBlocks) {
        // GEMM branch: W cast f32->f16 into LDS once per block, then MFMA.
        __shared__ unsigned int wsh[C * C / 2];   // 32KB
        const int tid = threadIdx.x;
        for (int i = tid; i < C * C / 8; i += 256) {
            const float4 a = ((const float4*)Wf0)[i * 2];
            const float4 bb = ((const float4*)Wf0)[i * 2 + 1];
            uint4 o;
            o.x = pkh2(a.x, a.y); o.y = pkh2(a.z, a.w);
            o.z = pkh2(bb.x, bb.y); o.w = pkh2(bb.z, bb.w);
            ((uint4*)wsh)[i] = o;
        }
        __syncthreads();

        const int lane = threadIdx.x & 63;
        const int wave = threadIdx.x >> 6;
        const int row0 = b * 64 + wave * 16;
        const int r = lane & 15, kg = lane >> 4;

        int arow = row0 + r;
        if (arow >= N) arow = N - 1;
        const float* xrow = x + (size_t)arow * C;
        f16x8 A[4];
#pragma unroll
        for (int kb = 0; kb < 4; ++kb) {
            const float4 p0 = ((const float4*)(xrow + kb * 32 + kg * 8))[0];
            const float4 p1 = ((const float4*)(xrow + kb * 32 + kg * 8))[1];
            f16x8 a;
            a[0] = (_Float16)p0.x; a[1] = (_Float16)p0.y;
            a[2] = (_Float16)p0.z; a[3] = (_Float16)p0.w;
            a[4] = (_Float16)p1.x; a[5] = (_Float16)p1.y;
            a[6] = (_Float16)p1.z; a[7] = (_Float16)p1.w;
            A[kb] = a;
        }

#pragma unroll
        for (int nt = 0; nt < 8; ++nt) {
            const uint4* wrow = (const uint4*)wsh + (size_t)(nt * 16 + r) * 16;
            f32x4 acc = {0.0f, 0.0f, 0.0f, 0.0f};
#pragma unroll
            for (int kb = 0; kb < 4; ++kb) {
                f16x8 B = __builtin_bit_cast(f16x8, wrow[kb * 4 + kg]);
                acc = __builtin_amdgcn_mfma_f32_16x16x32_f16(A[kb], B, acc, 0, 0, 0);
            }
            const int orow = row0 + kg * 4;
            const int ocol = nt * 16 + r;
#pragma unroll
            for (int i = 0; i < 4; ++i)
                if (orow + i < N)
                    xlh[(size_t)(orow + i) * C + ocol] =
                        __builtin_bit_cast(unsigned short, (_Float16)acc[i]);
        }
    } else if (b < nGemmBlocks + nCastBlocks) {
        // cast branch: emb f32 -> packed f16
        int i = (b - nGemmBlocks) * 256 + threadIdx.x;
        if (i >= totalA8) return;
        const float4 a = ((const float4*)embf)[i * 2];
        const float4 bb = ((const float4*)embf)[i * 2 + 1];
        uint4 o;
        o.x = pkh2(a.x, a.y); o.y = pkh2(a.z, a.w);
        o.z = pkh2(bb.x, bb.y); o.w = pkh2(bb.z, bb.w);
        ((uint4*)embh)[i] = o;
    } else {
        // binhist branch
        const int t = threadIdx.x;
        lh[t] = 0;
        __syncthreads();
        const int base = (b - nGemmBlocks - nCastBlocks) * 2048;
#pragma unroll
        for (int j = 0; j < 8; ++j) {
            const int e = base + j * 256 + t;
            if (e < E) atomicAdd(&lh[eidx[E + e] >> 8], 1);
        }
        __syncthreads();
        const int v = lh[t];
        if (v) atomicAdd(&binCounts[t], v);
    }
}

// ---------------------------------------------------------------------------
// k_bin: local LDS scan of binCounts; space claimed per (block,bin) on
// binAlloc; grouped contiguous record writes. Record u32: [31:24]=dst&255,
// [23:0]=src (needs N < 2^24).
// ---------------------------------------------------------------------------
__global__ __launch_bounds__(256) void k_bin(const int* __restrict__ eidx,
                                             const int* __restrict__ binCounts,
                                             int* __restrict__ binAlloc,
                                             unsigned int* __restrict__ binned, int E) {
    __shared__ int lh[256];
    __shared__ int sc[256];
    __shared__ int lb[256];
    const int t = threadIdx.x;
    const int v = binCounts[t];          // bins >= NB hold 0
    lh[t] = 0;
    sc[t] = v;
    __syncthreads();
    const int base = blockIdx.x * 2048;
    int bj[8], rj[8];
    unsigned int recj[8];
#pragma unroll
    for (int j = 0; j < 8; ++j) {
        const int e = base + j * 256 + t;
        bj[j] = -1;
        if (e < E) {
            const int s = eidx[e];
            const int d = eidx[E + e];
            bj[j] = d >> 8;
            recj[j] = ((unsigned)(d & 255) << 24) | (unsigned)s;
            rj[j] = atomicAdd(&lh[bj[j]], 1);
        }
    }
    __syncthreads();
    for (int o = 1; o < 256; o <<= 1) {
        int u = (t >= o) ? sc[t - o] : 0;
        __syncthreads();
        sc[t] += u;
        __syncthreads();
    }
    const int excl = sc[t] - v;          // global bin offset
    const int c = lh[t];
    if (c) lb[t] = excl + atomicAdd(&binAlloc[t], c);
    __syncthreads();
#pragma unroll
    for (int j = 0; j < 8; ++j) {
        if (bj[j] >= 0) binned[lb[bj[j]] + rj[j]] = recj[j];
    }
}

// ---------------------------------------------------------------------------
// k_place: one block per bin; local LDS scan of binCounts gives the record
// range; per-node counts + offsets via LDS scan; place src ids with LDS
// cursors (zero global atomics; writes land in the bin's L2-hot window).
// ---------------------------------------------------------------------------
__global__ __launch_bounds__(256) void k_place(const unsigned int* __restrict__ binned,
                                               const int* __restrict__ binCounts,
                                               int* __restrict__ offs,
                                               int* __restrict__ src_s,
                                               int N, int E, int NB) {
    __shared__ int sc[256];
    __shared__ int cnt[256];
    __shared__ int ts[256];
    __shared__ int cur[256];
    __shared__ int r0s, r1s;
    const int b = blockIdx.x;
    const int t = threadIdx.x;
    const int node0 = b * 256;
    const int v0 = binCounts[t];
    sc[t] = v0;
    cnt[t] = 0;
    __syncthreads();
    for (int o = 1; o < 256; o <<= 1) {
        int u = (t >= o) ? sc[t - o] : 0;
        __syncthreads();
        sc[t] += u;
        __syncthreads();
    }
    if (t == b) { r0s = sc[t] - v0; r1s = sc[t]; }
    __syncthreads();
    const int r0 = r0s, r1 = r1s;
    for (int i = r0 + t; i < r1; i += 256)
        atomicAdd(&cnt[binned[i] >> 24], 1);
    __syncthreads();
    const int v = cnt[t];
    ts[t] = v;
    __syncthreads();
    for (int o = 1; o < 256; o <<= 1) {
        int u = (t >= o) ? ts[t - o] : 0;
        __syncthreads();
        ts[t] += u;
        __syncthreads();
    }
    const int excl = r0 + ts[t] - v;
    if (node0 + t < N) offs[node0 + t] = excl;
    cur[t] = excl;
    __syncthreads();
    for (int i = r0 + t; i < r1; i += 256) {
        const unsigned int rec = binned[i];
        const int pos = atomicAdd(&cur[rec >> 24], 1);
        src_s[pos] = (int)(rec & 0xFFFFFFu);
    }
    if (b == NB - 1 && t == 0) offs[N] = E;
}

// ---------------------------------------------------------------------------
// K4: fused attention + online softmax + aggregation (+ BN partial stats).
// One wave per node; 64-edge src batches; 8-lane group dots (f16 v_dot2).
// SOFTWARE-PIPELINED: iteration k+1's emb row is prefetched before
// processing iteration k, overlapping gather latency with dot/reduce/exp.
// Epilogue: block LDS-reduce of its 4 nodes' outputs into 64-way-spread
// partial buffers (psum/psq).
// ---------------------------------------------------------------------------
__global__ __launch_bounds__(256) void k_agg(const unsigned int* __restrict__ xlh,
                                             const unsigned int* __restrict__ embh,
                                             const int* __restrict__ src_s,
                                             const int* __restrict__ offs,
                                             const float* __restrict__ bias,
                                             float* __restrict__ out,
                                             float* __restrict__ psum,
                                             float* __restrict__ psq, int N) {
    const int node = (int)((blockIdx.x * (size_t)blockDim.x + threadIdx.x) >> 6);
    const int lane = threadIdx.x & 63;
    const int wave = threadIdx.x >> 6;
    const bool active = node < N;
    float2 o2 = {0.0f, 0.0f};

    if (active) {
        const int g = lane >> 3;        // edge slot 0..7
        const int sl = lane & 7;        // sub-lane within 8-group
        const int s0 = offs[node], s1 = offs[node + 1];

        const uint4* erow = (const uint4*)(embh + (size_t)node * (C / 2));
        const uint4 e0 = erow[sl * 2], e1 = erow[sl * 2 + 1];

        // self-loop logit = ||emb[node]||^2
        float p = 0.0f;
        p = dot2acc(e0.x, e0.x, p); p = dot2acc(e0.y, e0.y, p);
        p = dot2acc(e0.z, e0.z, p); p = dot2acc(e0.w, e0.w, p);
        p = dot2acc(e1.x, e1.x, p); p = dot2acc(e1.y, e1.y, p);
        p = dot2acc(e1.z, e1.z, p); p = dot2acc(e1.w, e1.w, p);
        p += __shfl_xor(p, 4); p += __shfl_xor(p, 2); p += __shfl_xor(p, 1);

        float m = p;          // running max (self included)
        float wself = 1.0f;   // exp(self - m)
        float dex = 0.0f;     // hot-path denominator (wave-uniform)
        float dpart = 0.0f;   // per-group denominator partial
        const unsigned int xw = xlh[(size_t)node * (C / 2) + lane];
        float2 acc = {h2f_lo(xw), h2f_hi(xw)};   // wself * xl[node]

        for (int base = s0; base < s1; base += 64) {
            int mys = -1;
            if (base + lane < s1) mys = src_s[base + lane];
            const int iters = min(8, (s1 - base + 7) >> 3);

            // prologue: load iteration 0's row
            int sgc = __shfl(mys, g);
            {
                const int sac = (sgc >= 0) ? sgc : node;
                // issue gather for iter 0
            }
            const uint4* vrc = (const uint4*)(embh +
                                (size_t)((sgc >= 0) ? sgc : node) * (C / 2));
            uint4 v0c = vrc[sl * 2], v1c = vrc[sl * 2 + 1];

            for (int k = 0; k < iters; ++k) {
                // prefetch iteration k+1 (overlaps with processing of k)
                int sgn = -1;
                uint4 v0n, v1n;
                if (k + 1 < iters) {
                    sgn = __shfl(mys, (k + 1) * 8 + g);
                    const uint4* vrn = (const uint4*)(embh +
                                        (size_t)((sgn >= 0) ? sgn : node) * (C / 2));
                    v0n = vrn[sl * 2];
                    v1n = vrn[sl * 2 + 1];
                }

                // process current iteration's row
                float a = 0.0f;
                a = dot2acc(e0.x, v0c.x, a); a = dot2acc(e0.y, v0c.y, a);
                a = dot2acc(e0.z, v0c.z, a); a = dot2acc(e0.w, v0c.w, a);
                a = dot2acc(e1.x, v1c.x, a); a = dot2acc(e1.y, v1c.y, a);
                a = dot2acc(e1.z, v1c.z, a); a = dot2acc(e1.w, v1c.w, a);
                a += __shfl_xor(a, 4); a += __shfl_xor(a, 2); a += __shfl_xor(a, 1);

                const bool valid = sgc >= 0;
                const bool hot = valid && (a > m - 28.0f);
                if (__any(hot)) {
                    const unsigned long long bal = __ballot(hot);
#pragma unroll 1
                    for (int j = 0; j < 8; ++j) {
                        if (!((bal >> (j * 8)) & 1ULL)) continue;
                        const float aj = __shfl(a, j * 8);
                        const int sj = __shfl(mys, k * 8 + j);
                        if (aj > m) {            // wave-uniform rescale
                            const float cs = __expf(m - aj);
                            dpart *= cs; dex *= cs; wself *= cs;
                            acc.x *= cs; acc.y *= cs;
                            m = aj;
                        }
                        const float w = __expf(aj - m);
                        dex += w;
                        if (w > 1e-12f) {
                            const unsigned int u = xlh[(size_t)sj * (C / 2) + lane];
                            acc.x = fmaf(w, h2f_lo(u), acc.x);
                            acc.y = fmaf(w, h2f_hi(u), acc.y);
                        }
                    }
                }
                dpart += (valid && !hot) ? __expf(a - m) : 0.0f;

                sgc = sgn;
                v0c = v0n;
                v1c = v1n;
            }
        }

        float dg = dpart;
        dg += __shfl_xor(dg, 8); dg += __shfl_xor(dg, 16); dg += __shfl_xor(dg, 32);
        const float dtot = wself + dex + dg;
        const float inv = 1.0f / (dtot + 1e-16f);
        const int c = lane * 2;
        o2.x = fmaf(acc.x, inv, bias[c]);
        o2.y = fmaf(acc.y, inv, bias[c + 1]);
        ((float2*)(out + (size_t)node * C))[lane] = o2;
    }

    // ---- BN partial stats: block-level reduce over its 4 nodes, then
    // atomics into a 64-way-spread partial buffer.
    __shared__ float2 lsum[256];
    __shared__ float2 lsq[256];
    lsum[threadIdx.x] = o2;
    float2 q2v;
    q2v.x = o2.x * o2.x;
    q2v.y = o2.y * o2.y;
    lsq[threadIdx.x] = q2v;
    __syncthreads();
    if (wave == 0) {
        float2 S = lsum[lane], Q = lsq[lane];
#pragma unroll
        for (int j = 1; j < 4; ++j) {
            const float2 a = lsum[j * 64 + lane];
            const float2 b = lsq[j * 64 + lane];
            S.x += a.x; S.y += a.y;
            Q.x += b.x; Q.y += b.y;
        }
        const int slot = ((int)blockIdx.x & 63) * C + lane * 2;
        atomicAdd(&psum[slot],     S.x);
        atomicAdd(&psum[slot + 1], S.y);
        atomicAdd(&psq[slot],      Q.x);
        atomicAdd(&psq[slot + 1],  Q.y);
    }
}

// ---------------------------------------------------------------------------
// K6: BN stats finalize (per-block from 64x128 partials, L2-hot) + apply +
// ReLU, grid-stride. Replaces the separate bnreduce dispatch.
// ---------------------------------------------------------------------------
__global__ __launch_bounds__(256) void k_bnapply(float* __restrict__ out,
                                                 const float* __restrict__ psum,
                                                 const float* __restrict__ psq,
                                                 const float* __restrict__ gamma,
                                                 const float* __restrict__ beta,
                                                 int N) {
    __shared__ float smu[C];
    __shared__ float ssc[C];
    __shared__ float sbe[C];
    const int t = threadIdx.x;
    if (t < C) {
        float S = 0.0f, Q = 0.0f;
#pragma unroll 4
        for (int b = 0; b < 64; ++b) {
            S += psum[b * C + t];
            Q += psq[b * C + t];
        }
        const float invN = 1.0f / (float)N;
        const float mu = S * invN;
        const float var = fmaxf(fmaf(-mu, mu, Q * invN), 0.0f);
        smu[t] = mu;
        ssc[t] = gamma[t] / sqrtf(var + 1e-5f);
        sbe[t] = beta[t];
    }
    __syncthreads();
    const int total4 = N * (C / 4);
    const int stride = (int)gridDim.x * 256;
    for (int idx = (int)blockIdx.x * 256 + t; idx < total4; idx += stride) {
        const int c = (idx * 4) & 127;
        float4 v = ((const float4*)out)[idx];
        float r[4] = {v.x, v.y, v.z, v.w};
#pragma unroll
        for (int j = 0; j < 4; ++j)
            r[j] = fmaxf(fmaf(r[j] - smu[c + j], ssc[c + j], sbe[c + j]), 0.0f);
        float4 o = {r[0], r[1], r[2], r[3]};
        ((float4*)out)[idx] = o;
    }
}

// ---------------------------------------------------------------------------
extern "C" void kernel_launch(void* const* d_in, const int* in_sizes, int n_in,
                              void* d_out, int out_size, void* d_ws, size_t ws_size,
                              hipStream_t stream) {
    const float* x     = (const float*)d_in[0];
    const int*   eidx  = (const int*)d_in[1];   // [2][E]
    const float* emb   = (const float*)d_in[2];
    const float* W     = (const float*)d_in[3];
    const float* bias  = (const float*)d_in[4];
    const float* gamma = (const float*)d_in[5];
    const float* beta  = (const float*)d_in[6];
    const int N = in_sizes[0] / C;
    const int E = in_sizes[1] / 2;
    float* out = (float*)d_out;

    char* ws = (char*)d_ws;
    size_t off = 0;
    auto alloc = [&](size_t bytes) -> void* {
        void* p = ws + off;
        off = (off + bytes + 255) & ~(size_t)255;
        return p;
    };
    unsigned short* xlh  = (unsigned short*)alloc((size_t)N * C * 2);
    unsigned int*   embh = (unsigned int*)  alloc((size_t)N * C * 2);
    int*   src_s    = (int*)  alloc((size_t)E * 4);
    unsigned int* binned = (unsigned int*)alloc((size_t)E * 4);
    int*   offs     = (int*)  alloc((size_t)(N + 1) * 4);
    // contiguous zero-init region: binCounts + binAlloc + psum + psq
    char*  zbase    = (char*)alloc(0);
    int*   binCounts= (int*)  alloc(256 * 4);
    int*   binAlloc = (int*)  alloc(256 * 4);
    float* psum     = (float*)alloc(64 * C * 4);
    float* psq      = (float*)alloc(64 * C * 4);
    size_t zbytes   = (char*)ws + off - zbase;

    const int NB = (N + 255) / 256;              // 196 bins (<= 256)
    const int nEdgeBlocks = (E + 2047) / 2048;   // 391
    const int embTot8 = N * (C / 8);
    const int nGemmBlocks = (N + 63) / 64;       // 782
    const int nCastBlocks = (embTot8 + 255) / 256;

    hipMemsetAsync(zbase, 0, zbytes, stream);

    k_stageA <<<nGemmBlocks + nCastBlocks + nEdgeBlocks, 256, 0, stream>>>(
                 x, W, xlh, emb, embh, eidx, binCounts,
                 N, E, nGemmBlocks, nCastBlocks, embTot8);
    k_bin    <<<nEdgeBlocks,     256, 0, stream>>>(eidx, binCounts, binAlloc, binned, E);
    k_place  <<<NB,              256, 0, stream>>>(binned, binCounts, offs, src_s, N, E, NB);
    k_agg    <<<(int)(((size_t)N * 64 + 255) / 256), 256, 0, stream>>>(
                 (const unsigned int*)xlh, embh, src_s, offs, bias, out,
                 psum, psq, N);
    k_bnapply<<<512,             256, 0, stream>>>(out, psum, psq, gamma, beta, N);
}